// Round 5
// baseline (213.640 us; speedup 1.0000x reference)
//
#include <hip/hip_runtime.h>

// MaskUnitAttention fused kernel, MI355X gfx950.
// B=64, N=3136 (=64 tokens * 49 windows, window-fastest), DIM=96, DIM_OUT=192,
// HEADS=2, HEAD_DIM=96, Q_STRIDE=4, WINDOW_SIZE=16.
// v5: ONE WAVE OWNS ONE WINDOW, ZERO BARRIERS. v4's 7-barrier 4-wave phase
// chain was >95% stall (MfmaUtil 14%, per-block latency ~13-27us vs 0.3us of
// MFMA). Now each wave runs the whole pipeline on wave-private LDS (in-order
// per-wave LDS => no __syncthreads anywhere). Per-wave LDS cut to 10.75 KB by
// streaming transposes: K via [64][40] per 32-d chunk (consumed by S MFMAs
// immediately), V via [16][72] per d-tile, O via [16][40] per 32-ch chunk into
// proj accumulators. 128-thr blocks, 21.5 KB/block => 7 blocks/CU by LDS.
// All fragment layouts identical to the verified v4 conventions.

#define NW 49
#define NTOK 3136
#define DIM 96
#define DOUT 192

// ws layout (u16 element offsets)
#define WSQ 0
#define WSBQ 55296
#define WSP 55872
#define WSBP 92736
#define WSTOT 92928

typedef __bf16 bf16x8 __attribute__((ext_vector_type(8)));
typedef float f32x4 __attribute__((ext_vector_type(4)));
typedef unsigned short u16x8 __attribute__((ext_vector_type(8)));
typedef unsigned short u16x4 __attribute__((ext_vector_type(4)));

__device__ __forceinline__ unsigned short f2bf(float f) {
    return __builtin_bit_cast(unsigned short, (__bf16)f);   // RNE
}
__device__ __forceinline__ float bf2f(unsigned short h) {
    unsigned int u = ((unsigned int)h) << 16;
    return __builtin_bit_cast(float, u);
}

// Data sniff: x ~ N(0,1). bf16 data -> even-indexed u16s all have sane exponents.
// fp32 data -> even-indexed u16s are mantissa low-halves (uniform) -> ~16% sane.
__device__ __forceinline__ bool sniff_fp32(const unsigned short* x16) {
    int sane = 0;
    #pragma unroll
    for (int i = 0; i < 32; ++i) {
        unsigned e = ((unsigned)x16[2 * i] >> 7) & 0xFFu;
        sane += (e >= 100u && e <= 141u) ? 1 : 0;   // |v| in [2^-27, 2^14]
    }
    return sane < 24;
}

__device__ __forceinline__ bf16x8 ldb(const unsigned short* p) {
    return __builtin_bit_cast(bf16x8, *(const u16x8*)p);
}

// ---- pre-kernel: weights/biases -> bf16 in workspace (runs once, ~186 KB) ----
__global__ __launch_bounds__(256)
void conv_weights(const void* __restrict__ x,
                  const void* __restrict__ w_qkv, const void* __restrict__ b_qkv,
                  const void* __restrict__ w_proj, const void* __restrict__ b_proj,
                  unsigned short* __restrict__ ws)
{
    const bool f32m = sniff_fp32((const unsigned short*)x);
    int t = blockIdx.x * 256 + threadIdx.x;
    if (t >= WSTOT / 8) return;
    int off = t * 8;
    const void* src;
    int rel;
    if (off < WSBQ)      { src = w_qkv;  rel = off; }
    else if (off < WSP)  { src = b_qkv;  rel = off - WSBQ; }
    else if (off < WSBP) { src = w_proj; rel = off - WSP; }
    else                 { src = b_proj; rel = off - WSBP; }
    u16x8 v;
    if (f32m) {
        const float* p = (const float*)src + rel;
        f32x4 a = *(const f32x4*)p;
        f32x4 bb = *(const f32x4*)(p + 4);
        v[0] = f2bf(a[0]);  v[1] = f2bf(a[1]);  v[2] = f2bf(a[2]);  v[3] = f2bf(a[3]);
        v[4] = f2bf(bb[0]); v[5] = f2bf(bb[1]); v[6] = f2bf(bb[2]); v[7] = f2bf(bb[3]);
    } else {
        v = *(const u16x8*)((const unsigned short*)src + rel);
    }
    *(u16x8*)(ws + off) = v;
}

// ---- main kernel: 128 threads = 2 waves; each wave owns one (b, window) ----
__global__ __launch_bounds__(128, 2)
void mua_main(const void* __restrict__ x,
              const unsigned short* __restrict__ ws,
              void* __restrict__ out)
{
    const int tid  = threadIdx.x;
    const int wid  = tid >> 6;
    const int lane = tid & 63;
    const int quad = lane >> 4;
    const int l16  = lane & 15;
    const int win  = blockIdx.x * 2 + wid;
    const int b    = win / NW;
    const int wi   = win - b * NW;

    // Per-wave LDS slice: 5376 u16 = 10752 B (16B-aligned; strides 40/72/104
    // u16 give <=2-way bank aliasing on all accesses).
    //   kbuf [64][40] @0     : K-transpose, one 32-d chunk at a time
    //   vbuf [16][72] @0     : V d-tile (reuses kbuf region after S)
    //   obuf [16][40] @1280  : O-transpose per 32-ch chunk (disjoint from vbuf)
    //   qp   [16][104]@2560  : pooled Q, one head at a time
    //   pbuf [16][72] @4224  : P, one head at a time
    __shared__ __attribute__((aligned(16))) unsigned short lds[10752];
    unsigned short* kbuf = lds + wid * 5376;
    unsigned short* vbuf = kbuf;
    unsigned short* obuf = kbuf + 1280;
    unsigned short* qp   = kbuf + 2560;
    unsigned short* pbuf = kbuf + 4224;

    const bool f32m = sniff_fp32((const unsigned short*)x);

    // ---- x A-fragments straight from global (no staging): afr[mt][ks] =
    //      x[mt*16+l16][ks*32+quad*8 ..+8]; per row 4 quads read 64B contiguous.
    bf16x8 afr[4][3];
    {
        const size_t xoff = ((size_t)b * NTOK + wi) * DIM;
        if (f32m) {
            #pragma unroll
            for (int mt = 0; mt < 4; ++mt)
                #pragma unroll
                for (int ks = 0; ks < 3; ++ks) {
                    const float* p = (const float*)x + xoff
                                   + (size_t)(mt * 16 + l16) * (NW * DIM) + ks * 32 + quad * 8;
                    f32x4 a = *(const f32x4*)p;
                    f32x4 bb = *(const f32x4*)(p + 4);
                    u16x8 r;
                    r[0] = f2bf(a[0]);  r[1] = f2bf(a[1]);  r[2] = f2bf(a[2]);  r[3] = f2bf(a[3]);
                    r[4] = f2bf(bb[0]); r[5] = f2bf(bb[1]); r[6] = f2bf(bb[2]); r[7] = f2bf(bb[3]);
                    afr[mt][ks] = __builtin_bit_cast(bf16x8, r);
                }
        } else {
            #pragma unroll
            for (int mt = 0; mt < 4; ++mt)
                #pragma unroll
                for (int ks = 0; ks < 3; ++ks) {
                    const unsigned short* p = (const unsigned short*)x + xoff
                                   + (size_t)(mt * 16 + l16) * (NW * DIM) + ks * 32 + quad * 8;
                    afr[mt][ks] = ldb(p);
                }
        }
    }

    // proj accumulators, span both heads (out c-tile i: c = i*16 + l16)
    f32x4 pacc[12];
    #pragma unroll
    for (int i = 0; i < 12; ++i) pacc[i] = (f32x4){0.f, 0.f, 0.f, 0.f};

    for (int h = 0; h < 2; ++h) {
        // ---- Q: 6 ch-tiles, maxpool over mt, qp[j=quad*4+r][d] ----
        #pragma unroll
        for (int ct = 0; ct < 6; ++ct) {
            const int c = h * 96 + ct * 16 + l16;
            bf16x8 wb[3];
            #pragma unroll
            for (int ks = 0; ks < 3; ++ks)
                wb[ks] = ldb(ws + WSQ + c * 96 + ks * 32 + quad * 8);
            f32x4 acc[4];
            #pragma unroll
            for (int mt = 0; mt < 4; ++mt) {
                acc[mt] = (f32x4){0.f, 0.f, 0.f, 0.f};
                #pragma unroll
                for (int ks = 0; ks < 3; ++ks)
                    acc[mt] = __builtin_amdgcn_mfma_f32_16x16x32_bf16(afr[mt][ks], wb[ks], acc[mt], 0, 0, 0);
            }
            const float bias = bf2f(ws[WSBQ + c]);
            #pragma unroll
            for (int r = 0; r < 4; ++r) {
                float m = fmaxf(fmaxf(acc[0][r], acc[1][r]), fmaxf(acc[2][r], acc[3][r])) + bias;
                qp[(quad * 4 + r) * 104 + ct * 16 + l16] = f2bf(m);
            }
        }
        // qa fragments (reads follow qp writes, same-wave in-order LDS)
        bf16x8 qa[3];
        #pragma unroll
        for (int ksp = 0; ksp < 3; ++ksp)
            qa[ksp] = ldb(&qp[l16 * 104 + ksp * 32 + quad * 8]);

        // ---- K + S: per 32-d chunk, transpose K through kbuf, S-MFMA ----
        f32x4 s[4];
        #pragma unroll
        for (int nt = 0; nt < 4; ++nt) s[nt] = (f32x4){0.f, 0.f, 0.f, 0.f};
        #pragma unroll
        for (int ksp = 0; ksp < 3; ++ksp) {
            #pragma unroll
            for (int half = 0; half < 2; ++half) {
                const int c = 192 + h * 96 + ksp * 32 + half * 16 + l16;
                bf16x8 wb[3];
                #pragma unroll
                for (int ks = 0; ks < 3; ++ks)
                    wb[ks] = ldb(ws + WSQ + c * 96 + ks * 32 + quad * 8);
                f32x4 acc[4];
                #pragma unroll
                for (int mt = 0; mt < 4; ++mt) {
                    acc[mt] = (f32x4){0.f, 0.f, 0.f, 0.f};
                    #pragma unroll
                    for (int ks = 0; ks < 3; ++ks)
                        acc[mt] = __builtin_amdgcn_mfma_f32_16x16x32_bf16(afr[mt][ks], wb[ks], acc[mt], 0, 0, 0);
                }
                const float bias = bf2f(ws[WSBQ + c]);
                #pragma unroll
                for (int mt = 0; mt < 4; ++mt)
                    #pragma unroll
                    for (int r = 0; r < 4; ++r)
                        kbuf[(mt * 16 + quad * 4 + r) * 40 + half * 16 + l16] = f2bf(acc[mt][r] + bias);
            }
            #pragma unroll
            for (int nt = 0; nt < 4; ++nt) {
                bf16x8 kb = ldb(&kbuf[(nt * 16 + l16) * 40 + quad * 8]);
                s[nt] = __builtin_amdgcn_mfma_f32_16x16x32_bf16(qa[ksp], kb, s[nt], 0, 0, 0);
            }
        }

        // ---- softmax (rows j = quad*4+r; cols on l16/nt) ----
        float rinv[4];
        const float cexp = 0.10206207261596576f * 1.4426950408889634f;  // 96^-0.5 * log2e
        #pragma unroll
        for (int r = 0; r < 4; ++r) {
            float m = fmaxf(fmaxf(s[0][r], s[1][r]), fmaxf(s[2][r], s[3][r]));
            m = fmaxf(m, __shfl_xor(m, 1));
            m = fmaxf(m, __shfl_xor(m, 2));
            m = fmaxf(m, __shfl_xor(m, 4));
            m = fmaxf(m, __shfl_xor(m, 8));
            float sum = 0.f;
            #pragma unroll
            for (int nt = 0; nt < 4; ++nt) {
                s[nt][r] = exp2f((s[nt][r] - m) * cexp);
                sum += s[nt][r];
            }
            sum += __shfl_xor(sum, 1);
            sum += __shfl_xor(sum, 2);
            sum += __shfl_xor(sum, 4);
            sum += __shfl_xor(sum, 8);
            rinv[r] = 1.0f / sum;
        }
        #pragma unroll
        for (int nt = 0; nt < 4; ++nt)
            #pragma unroll
            for (int r = 0; r < 4; ++r)
                pbuf[(quad * 4 + r) * 72 + nt * 16 + l16] = f2bf(s[nt][r]);
        bf16x8 pa[2];
        #pragma unroll
        for (int ks2 = 0; ks2 < 2; ++ks2)
            pa[ks2] = ldb(&pbuf[l16 * 72 + ks2 * 32 + quad * 8]);

        // ---- V + PV + proj-accumulate, per 32-ch chunk dp ----
        #pragma unroll
        for (int dp = 0; dp < 3; ++dp) {
            #pragma unroll
            for (int half = 0; half < 2; ++half) {
                const int ct = dp * 2 + half;
                const int c = 384 + h * 96 + ct * 16 + l16;
                bf16x8 wb[3];
                #pragma unroll
                for (int ks = 0; ks < 3; ++ks)
                    wb[ks] = ldb(ws + WSQ + c * 96 + ks * 32 + quad * 8);
                f32x4 acc[4];
                #pragma unroll
                for (int mt = 0; mt < 4; ++mt) {
                    acc[mt] = (f32x4){0.f, 0.f, 0.f, 0.f};
                    #pragma unroll
                    for (int ks = 0; ks < 3; ++ks)
                        acc[mt] = __builtin_amdgcn_mfma_f32_16x16x32_bf16(afr[mt][ks], wb[ks], acc[mt], 0, 0, 0);
                }
                const float bias = bf2f(ws[WSBQ + c]);
                // V tile transposed [d=l16][t]: 4 consecutive t per (lane,mt)
                #pragma unroll
                for (int mt = 0; mt < 4; ++mt) {
                    u16x4 pk;
                    #pragma unroll
                    for (int r = 0; r < 4; ++r) pk[r] = f2bf(acc[mt][r] + bias);
                    *(u16x4*)&vbuf[l16 * 72 + mt * 16 + quad * 4] = pk;
                }
                // PV for this d-tile
                f32x4 oacc = (f32x4){0.f, 0.f, 0.f, 0.f};
                #pragma unroll
                for (int ks2 = 0; ks2 < 2; ++ks2) {
                    bf16x8 vb = ldb(&vbuf[l16 * 72 + ks2 * 32 + quad * 8]);
                    oacc = __builtin_amdgcn_mfma_f32_16x16x32_bf16(pa[ks2], vb, oacc, 0, 0, 0);
                }
                #pragma unroll
                for (int r = 0; r < 4; ++r)
                    obuf[(quad * 4 + r) * 40 + half * 16 + l16] = f2bf(oacc[r] * rinv[r]);
            }
            // O chunk as A-frag; accumulate proj over this 32-ch k-chunk
            bf16x8 oa = ldb(&obuf[l16 * 40 + quad * 8]);
            const int ksg = h * 3 + dp;
            #pragma unroll
            for (int i = 0; i < 12; ++i) {
                const int c = i * 16 + l16;
                bf16x8 wb = ldb(ws + WSP + c * 192 + ksg * 32 + quad * 8);
                pacc[i] = __builtin_amdgcn_mfma_f32_16x16x32_bf16(oa, wb, pacc[i], 0, 0, 0);
            }
        }
    }

    // ---- epilogue: out = pacc + bias; row = b*784 + j*49 + wi, j = quad*4+r ----
    #pragma unroll
    for (int i = 0; i < 12; ++i) {
        const int c = i * 16 + l16;
        const float bias = bf2f(ws[WSBP + c]);
        #pragma unroll
        for (int r = 0; r < 4; ++r) {
            const int m = quad * 4 + r;
            const size_t idx = ((size_t)(b * 784 + m * NW + wi)) * DOUT + c;
            if (f32m) ((float*)out)[idx] = pacc[i][r] + bias;
            else      ((unsigned short*)out)[idx] = f2bf(pacc[i][r] + bias);
        }
    }
}

extern "C" void kernel_launch(void* const* d_in, const int* in_sizes, int n_in,
                              void* d_out, int out_size, void* d_ws, size_t ws_size,
                              hipStream_t stream) {
    const void* x      = d_in[0];
    const void* w_qkv  = d_in[1];
    const void* b_qkv  = d_in[2];
    const void* w_proj = d_in[3];
    const void* b_proj = d_in[4];
    unsigned short* ws = (unsigned short*)d_ws;

    // Pre-kernel: convert weights/biases to bf16 into workspace (stream-ordered).
    dim3 gridc((WSTOT / 8 + 255) / 256), blockc(256);
    hipLaunchKernelGGL(conv_weights, gridc, blockc, 0, stream,
                       x, w_qkv, b_qkv, w_proj, b_proj, ws);

    dim3 grid(NTOK / 2), block(128);   // 1568 blocks x 2 waves = 3136 windows
    hipLaunchKernelGGL(mua_main, grid, block, 0, stream, x, ws, d_out);
}

// Round 6
// 208.057 us; speedup vs baseline: 1.0268x; 1.0268x over previous
//
#include <hip/hip_runtime.h>

// MaskUnitAttention fused kernel, MI355X gfx950.
// B=64, N=3136 (=64 tokens * 49 windows, window-fastest), DIM=96, DIM_OUT=192,
// HEADS=2, HEAD_DIM=96, Q_STRIDE=4, WINDOW_SIZE=16.
// v6: v4 skeleton (best measured: 81.9us; 4 waves/block, K-V LDS time-share,
// rotating weight buffers, (256,2)) with the serial head trimmed:
//   - x-staging phase REMOVED: afr fragments load directly global->regs
//     (pattern proven correct in v5; x is L3-resident). Kills 2 of 6 barriers
//     and the LDS round-trip at block start.
//   - epilogue uses per-row pointers + small immediate offsets (was 64-bit
//     index math per store).
// v5 post-mortem: 1 wave/window zero-barrier design regressed (144us) — only
// 12.25 waves/CU total work, dispatch time = one wave's huge serial latency.
// Phase-parallel waves + many blocks is the right skeleton; keep it.

#define NW 49
#define NTOK 3136
#define DIM 96
#define DOUT 192

// ws layout (u16 element offsets)
#define WSQ 0
#define WSBQ 55296
#define WSP 55872
#define WSBP 92736
#define WSTOT 92928

typedef __bf16 bf16x8 __attribute__((ext_vector_type(8)));
typedef float f32x4 __attribute__((ext_vector_type(4)));
typedef unsigned short u16x8 __attribute__((ext_vector_type(8)));
typedef unsigned short u16x4 __attribute__((ext_vector_type(4)));

__device__ __forceinline__ unsigned short f2bf(float f) {
    return __builtin_bit_cast(unsigned short, (__bf16)f);   // RNE
}
__device__ __forceinline__ float bf2f(unsigned short h) {
    unsigned int u = ((unsigned int)h) << 16;
    return __builtin_bit_cast(float, u);
}

// Data sniff: x ~ N(0,1). bf16 data -> even-indexed u16s all have sane exponents.
// fp32 data -> even-indexed u16s are mantissa low-halves (uniform) -> ~16% sane.
__device__ __forceinline__ bool sniff_fp32(const unsigned short* x16) {
    int sane = 0;
    #pragma unroll
    for (int i = 0; i < 32; ++i) {
        unsigned e = ((unsigned)x16[2 * i] >> 7) & 0xFFu;
        sane += (e >= 100u && e <= 141u) ? 1 : 0;   // |v| in [2^-27, 2^14]
    }
    return sane < 24;
}

__device__ __forceinline__ bf16x8 ldb(const unsigned short* p) {
    return __builtin_bit_cast(bf16x8, *(const u16x8*)p);
}

// ---- pre-kernel: weights/biases -> bf16 in workspace (runs once, ~186 KB) ----
__global__ __launch_bounds__(256)
void conv_weights(const void* __restrict__ x,
                  const void* __restrict__ w_qkv, const void* __restrict__ b_qkv,
                  const void* __restrict__ w_proj, const void* __restrict__ b_proj,
                  unsigned short* __restrict__ ws)
{
    const bool f32m = sniff_fp32((const unsigned short*)x);
    int t = blockIdx.x * 256 + threadIdx.x;
    if (t >= WSTOT / 8) return;
    int off = t * 8;
    const void* src;
    int rel;
    if (off < WSBQ)      { src = w_qkv;  rel = off; }
    else if (off < WSP)  { src = b_qkv;  rel = off - WSBQ; }
    else if (off < WSBP) { src = w_proj; rel = off - WSP; }
    else                 { src = b_proj; rel = off - WSBP; }
    u16x8 v;
    if (f32m) {
        const float* p = (const float*)src + rel;
        f32x4 a = *(const f32x4*)p;
        f32x4 bb = *(const f32x4*)(p + 4);
        v[0] = f2bf(a[0]);  v[1] = f2bf(a[1]);  v[2] = f2bf(a[2]);  v[3] = f2bf(a[3]);
        v[4] = f2bf(bb[0]); v[5] = f2bf(bb[1]); v[6] = f2bf(bb[2]); v[7] = f2bf(bb[3]);
    } else {
        v = *(const u16x8*)((const unsigned short*)src + rel);
    }
    *(u16x8*)(ws + off) = v;
}

// ---- main fused kernel: one block per (b, window) ----
__global__ __launch_bounds__(256, 2)
void mua_main(const void* __restrict__ x,
              const unsigned short* __restrict__ ws,
              void* __restrict__ out)
{
    const int bid = blockIdx.x;
    const int b   = bid / NW;
    const int wi  = bid - b * NW;
    const int tid  = threadIdx.x;
    const int wave = tid >> 6;
    const int lane = tid & 63;
    const int quad = lane >> 4;
    const int l16  = lane & 15;

    // 38912 B LDS. Padded strides (104/72/200 u16) are 16B-multiples, <=2-way
    // bank aliasing (free). Region 1 (u16 [0,13824)) is time-shared:
    //   k_s [2][64][104]   (written in GEMM1, dead after B4)
    //   v_s [2][96][72]    (written after B4)
    // qp_s [2][16][104] @13824 (o_s [16][200] aliases; qp dead after B4)
    // p_s  [2][16][72]  @17152
    __shared__ __attribute__((aligned(16))) unsigned short lds[19456];
    unsigned short* k_s  = lds;
    unsigned short* v_s  = lds;
    unsigned short* qp_s = lds + 13824;
    unsigned short* o_s  = lds + 13824;
    unsigned short* p_s  = lds + 17152;

    // ---- preload wq tiles 0..2 (3-deep rotation, 36 regs) + all biases ----
    // Tile tt = nt*4 + wave: nt 0..2 -> q tiles (0..11), nt 3..5 -> k (12..23);
    // interleave balances q-pool vs k-store epilogue cost across waves.
    bf16x8 wq[3][3];
    float  biasq[6];
    #pragma unroll
    for (int nt = 0; nt < 3; ++nt) {
        const int c = (nt * 4 + wave) * 16 + l16;
        #pragma unroll
        for (int ks = 0; ks < 3; ++ks)
            wq[nt][ks] = ldb(ws + WSQ + c * 96 + ks * 32 + quad * 8);
    }
    #pragma unroll
    for (int nt = 0; nt < 6; ++nt)
        biasq[nt] = bf2f(ws[WSBQ + (nt * 4 + wave) * 16 + l16]);

    const bool f32m = sniff_fp32((const unsigned short*)x);

    // ---- x A-fragments straight from global (no staging, no barrier):
    //      afr[mt][ks] = x[mt*16+l16][ks*32+quad*8 ..+8]  (proven in v5) ----
    bf16x8 afr[4][3];
    {
        const size_t xoff = ((size_t)b * NTOK + wi) * DIM;
        if (f32m) {
            #pragma unroll
            for (int mt = 0; mt < 4; ++mt)
                #pragma unroll
                for (int ks = 0; ks < 3; ++ks) {
                    const float* p = (const float*)x + xoff
                                   + (size_t)(mt * 16 + l16) * (NW * DIM) + ks * 32 + quad * 8;
                    f32x4 a = *(const f32x4*)p;
                    f32x4 bb = *(const f32x4*)(p + 4);
                    u16x8 r;
                    r[0] = f2bf(a[0]);  r[1] = f2bf(a[1]);  r[2] = f2bf(a[2]);  r[3] = f2bf(a[3]);
                    r[4] = f2bf(bb[0]); r[5] = f2bf(bb[1]); r[6] = f2bf(bb[2]); r[7] = f2bf(bb[3]);
                    afr[mt][ks] = __builtin_bit_cast(bf16x8, r);
                }
        } else {
            #pragma unroll
            for (int mt = 0; mt < 4; ++mt)
                #pragma unroll
                for (int ks = 0; ks < 3; ++ks) {
                    const unsigned short* p = (const unsigned short*)x + xoff
                                   + (size_t)(mt * 16 + l16) * (NW * DIM) + ks * 32 + quad * 8;
                    afr[mt][ks] = ldb(p);
                }
        }
    }

    // ---- phase 1: q+k channels of qkv; wq slot nt%3 refilled with tile nt+3.
    //      No barrier needed before: k_s/qp_s not yet read by anyone. ----
    #pragma unroll
    for (int nt = 0; nt < 6; ++nt) {
        const int slot = nt % 3;   // compile-time after unroll
        f32x4 acc[4];
        #pragma unroll
        for (int mt = 0; mt < 4; ++mt) {
            acc[mt] = (f32x4){0.f, 0.f, 0.f, 0.f};
            #pragma unroll
            for (int ks = 0; ks < 3; ++ks)
                acc[mt] = __builtin_amdgcn_mfma_f32_16x16x32_bf16(afr[mt][ks], wq[slot][ks], acc[mt], 0, 0, 0);
        }
        if (nt < 3) {   // refill slot with tile nt+3 (WAR on slot orders after MFMAs)
            const int c2 = ((nt + 3) * 4 + wave) * 16 + l16;
            #pragma unroll
            for (int ks = 0; ks < 3; ++ks)
                wq[slot][ks] = ldb(ws + WSQ + c2 * 96 + ks * 32 + quad * 8);
        }
        // C-layout: col(channel) = l16, row(token) = quad*4 + r (+ mt*16)
        const int tt = nt * 4 + wave;
        const float bias = biasq[nt];
        if (nt < 3) {
            // q tiles: maxpool over the 4 M-tiles (pool groups are exactly mt)
            const int hd = tt / 6;
            const int d  = (tt % 6) * 16 + l16;
            #pragma unroll
            for (int r = 0; r < 4; ++r) {
                float m = fmaxf(fmaxf(acc[0][r], acc[1][r]), fmaxf(acc[2][r], acc[3][r])) + bias;
                qp_s[(hd * 16 + quad * 4 + r) * 104 + d] = f2bf(m);
            }
        } else {
            const int tk = tt - 12;
            const int hd = tk / 6;
            const int d  = (tk % 6) * 16 + l16;
            #pragma unroll
            for (int mt = 0; mt < 4; ++mt)
                #pragma unroll
                for (int r = 0; r < 4; ++r)
                    k_s[hd * 6656 + (mt * 16 + quad * 4 + r) * 104 + d] = f2bf(acc[mt][r] + bias);
        }
    }
    __syncthreads();   // B3: qp/k ready

    // ---- phase 2: S = qp @ k^T, row softmax (rows j = quad*4+r, cols on l16/nt) ----
    const int h   = wave >> 1;
    const int sub = wave & 1;
    bf16x8 qa[3];
    #pragma unroll
    for (int ks = 0; ks < 3; ++ks)
        qa[ks] = ldb(&qp_s[(h * 16 + l16) * 104 + ks * 32 + quad * 8]);
    f32x4 s[4];
    #pragma unroll
    for (int nt = 0; nt < 4; ++nt) {
        s[nt] = (f32x4){0.f, 0.f, 0.f, 0.f};
        #pragma unroll
        for (int ks = 0; ks < 3; ++ks) {
            bf16x8 kb = ldb(&k_s[h * 6656 + (nt * 16 + l16) * 104 + ks * 32 + quad * 8]);
            s[nt] = __builtin_amdgcn_mfma_f32_16x16x32_bf16(qa[ks], kb, s[nt], 0, 0, 0);
        }
    }
    float rinv[4];
    const float cexp = 0.10206207261596576f * 1.4426950408889634f;  // 96^-0.5 * log2e
    #pragma unroll
    for (int r = 0; r < 4; ++r) {
        float m = fmaxf(fmaxf(s[0][r], s[1][r]), fmaxf(s[2][r], s[3][r]));
        m = fmaxf(m, __shfl_xor(m, 1));
        m = fmaxf(m, __shfl_xor(m, 2));
        m = fmaxf(m, __shfl_xor(m, 4));
        m = fmaxf(m, __shfl_xor(m, 8));
        float sum = 0.f;
        #pragma unroll
        for (int nt = 0; nt < 4; ++nt) {
            s[nt][r] = exp2f((s[nt][r] - m) * cexp);
            sum += s[nt][r];
        }
        sum += __shfl_xor(sum, 1);
        sum += __shfl_xor(sum, 2);
        sum += __shfl_xor(sum, 4);
        sum += __shfl_xor(sum, 8);
        rinv[r] = 1.0f / sum;
    }
    if (sub == 0) {   // wave pair computes S redundantly; one writer
        #pragma unroll
        for (int nt = 0; nt < 4; ++nt)
            #pragma unroll
            for (int r = 0; r < 4; ++r)
                p_s[h * 1152 + (quad * 4 + r) * 72 + nt * 16 + l16] = f2bf(s[nt][r]);
    }

    // ---- preload v-weight tiles 0,1 (2-deep rotation); hide under B4 wait ----
    bf16x8 wv[2][3];
    float  biasv[3];
    #pragma unroll
    for (int i = 0; i < 2; ++i) {
        const int c = 384 + (i * 4 + wave) * 16 + l16;
        #pragma unroll
        for (int ks = 0; ks < 3; ++ks)
            wv[i][ks] = ldb(ws + WSQ + c * 96 + ks * 32 + quad * 8);
    }
    #pragma unroll
    for (int i = 0; i < 3; ++i)
        biasv[i] = bf2f(ws[WSBQ + 384 + (i * 4 + wave) * 16 + l16]);
    __syncthreads();   // B4: P ready; k and qp dead -> v/o may overwrite

    // ---- phase 3: v channels (afr still in regs); v transposed [head][d][t] ----
    #pragma unroll
    for (int i = 0; i < 3; ++i) {
        const int slot = i & 1;   // compile-time after unroll
        f32x4 acc[4];
        #pragma unroll
        for (int mt = 0; mt < 4; ++mt) {
            acc[mt] = (f32x4){0.f, 0.f, 0.f, 0.f};
            #pragma unroll
            for (int ks = 0; ks < 3; ++ks)
                acc[mt] = __builtin_amdgcn_mfma_f32_16x16x32_bf16(afr[mt][ks], wv[slot][ks], acc[mt], 0, 0, 0);
        }
        if (i == 0) {   // refill slot 0 with tile 2
            const int c2 = 384 + (2 * 4 + wave) * 16 + l16;
            #pragma unroll
            for (int ks = 0; ks < 3; ++ks)
                wv[0][ks] = ldb(ws + WSQ + c2 * 96 + ks * 32 + quad * 8);
        }
        const int tv = i * 4 + wave;
        const int hd = tv / 6;
        const int d  = (tv % 6) * 16 + l16;
        const float bias = biasv[i];
        #pragma unroll
        for (int mt = 0; mt < 4; ++mt) {
            u16x4 pk;
            #pragma unroll
            for (int r = 0; r < 4; ++r) pk[r] = f2bf(acc[mt][r] + bias);
            *(u16x4*)&v_s[hd * 6912 + d * 72 + mt * 16 + quad * 4] = pk;
        }
    }

    // ---- hoist proj weights/biases (afr/wv dead); land under B4b + PV ----
    const int cbase = wave * 48;
    bf16x8 wpr[3][6];
    float  biasp[3];
    #pragma unroll
    for (int i = 0; i < 3; ++i) {
        const int c = cbase + i * 16 + l16;
        #pragma unroll
        for (int ks = 0; ks < 6; ++ks)
            wpr[i][ks] = ldb(ws + WSP + c * 192 + ks * 32 + quad * 8);
        biasp[i] = bf2f(ws[WSBP + c]);
    }
    __syncthreads();   // B4b: v ready

    // ---- phase 4: O = P @ V (3 of 6 d-tiles per sub-wave), scale rows by 1/sum ----
    bf16x8 pa[2];
    #pragma unroll
    for (int ks = 0; ks < 2; ++ks)
        pa[ks] = ldb(&p_s[h * 1152 + l16 * 72 + ks * 32 + quad * 8]);
    #pragma unroll
    for (int i = 0; i < 3; ++i) {
        const int n0 = (sub * 3 + i) * 16;
        f32x4 oacc = (f32x4){0.f, 0.f, 0.f, 0.f};
        #pragma unroll
        for (int ks = 0; ks < 2; ++ks) {
            bf16x8 vb = ldb(&v_s[h * 6912 + (n0 + l16) * 72 + ks * 32 + quad * 8]);
            oacc = __builtin_amdgcn_mfma_f32_16x16x32_bf16(pa[ks], vb, oacc, 0, 0, 0);
        }
        #pragma unroll
        for (int r = 0; r < 4; ++r)
            o_s[(quad * 4 + r) * 200 + h * 96 + n0 + l16] = f2bf(oacc[r] * rinv[r]);
    }
    __syncthreads();   // B5: o ready

    // ---- phase 5: out = o @ w_proj^T + b_proj; wave owns 48 of 192 channels ----
    bf16x8 oa[6];
    #pragma unroll
    for (int ks = 0; ks < 6; ++ks)
        oa[ks] = ldb(&o_s[l16 * 200 + ks * 32 + quad * 8]);
    f32x4 res[3];
    #pragma unroll
    for (int i = 0; i < 3; ++i) {
        res[i] = (f32x4){0.f, 0.f, 0.f, 0.f};
        #pragma unroll
        for (int ks = 0; ks < 6; ++ks)
            res[i] = __builtin_amdgcn_mfma_f32_16x16x32_bf16(oa[ks], wpr[i][ks], res[i], 0, 0, 0);
    }
    // Per-row pointer + immediate offsets (32-bit math; rows = b*784 + m*49 + wi)
    const unsigned rowelem = (unsigned)(b * 784 + wi) * DOUT + cbase + l16;
    if (f32m) {
        float* po = (float*)out + rowelem;
        #pragma unroll
        for (int r = 0; r < 4; ++r) {
            float* pr = po + (unsigned)(quad * 4 + r) * (NW * DOUT);
            #pragma unroll
            for (int i = 0; i < 3; ++i) pr[i * 16] = res[i][r] + biasp[i];
        }
    } else {
        unsigned short* po = (unsigned short*)out + rowelem;
        #pragma unroll
        for (int r = 0; r < 4; ++r) {
            unsigned short* pr = po + (unsigned)(quad * 4 + r) * (NW * DOUT);
            #pragma unroll
            for (int i = 0; i < 3; ++i) pr[i * 16] = f2bf(res[i][r] + biasp[i]);
        }
    }
}

extern "C" void kernel_launch(void* const* d_in, const int* in_sizes, int n_in,
                              void* d_out, int out_size, void* d_ws, size_t ws_size,
                              hipStream_t stream) {
    const void* x      = d_in[0];
    const void* w_qkv  = d_in[1];
    const void* b_qkv  = d_in[2];
    const void* w_proj = d_in[3];
    const void* b_proj = d_in[4];
    unsigned short* ws = (unsigned short*)d_ws;

    // Pre-kernel: convert weights/biases to bf16 into workspace (stream-ordered).
    dim3 gridc((WSTOT / 8 + 255) / 256), blockc(256);
    hipLaunchKernelGGL(conv_weights, gridc, blockc, 0, stream,
                       x, w_qkv, b_qkv, w_proj, b_proj, ws);

    dim3 grid(64 * NW), block(256);
    hipLaunchKernelGGL(mua_main, grid, block, 0, stream, x, ws, d_out);
}

// Round 7
// 179.411 us; speedup vs baseline: 1.1908x; 1.1597x over previous
//
#include <hip/hip_runtime.h>

// MaskUnitAttention fused kernel, MI355X gfx950.
// B=64, N=3136 (=64 tokens * 49 windows, window-fastest), DIM=96, DIM_OUT=192,
// HEADS=2, HEAD_DIM=96, Q_STRIDE=4, WINDOW_SIZE=16.
// v7: v4 skeleton (81.9us proven: x-staged LDS, 4 waves, rotating weight regs,
// (256,2)) with LDS cut 38.9KB -> 31.2KB => 5 blocks/CU:
//   - S computed TRANSPOSED via MFMA operand swap (same loads); softmax is
//     per-lane + 2 cross-quad shuffles; P assembled in-register for PV
//     (cvt_pk + 16 __shfl) => p_s region deleted.
//   - K stored swizzled stride 96 (col = ((d>>3)^(row&3))*8 + (d&7)).
//   - V stored swizzled stride 64 (t-block ^= d&7), u16x4 writes 8B-aligned.
// v6 post-mortem: direct per-wave x loads = 4x redundant VMEM, regressed;
// x-staging restored.

#define NW 49
#define NTOK 3136
#define DIM 96
#define DOUT 192

// ws layout (u16 element offsets)
#define WSQ 0
#define WSBQ 55296
#define WSP 55872
#define WSBP 92736
#define WSTOT 92928

typedef __bf16 bf16x8 __attribute__((ext_vector_type(8)));
typedef float f32x4 __attribute__((ext_vector_type(4)));
typedef unsigned short u16x8 __attribute__((ext_vector_type(8)));
typedef unsigned short u16x4 __attribute__((ext_vector_type(4)));
typedef unsigned int   u32x4 __attribute__((ext_vector_type(4)));

__device__ __forceinline__ unsigned short f2bf(float f) {
    return __builtin_bit_cast(unsigned short, (__bf16)f);   // RNE
}
__device__ __forceinline__ float bf2f(unsigned short h) {
    unsigned int u = ((unsigned int)h) << 16;
    return __builtin_bit_cast(float, u);
}

// Data sniff: x ~ N(0,1). bf16 data -> even-indexed u16s all have sane exponents.
// fp32 data -> even-indexed u16s are mantissa low-halves (uniform) -> ~16% sane.
__device__ __forceinline__ bool sniff_fp32(const unsigned short* x16) {
    int sane = 0;
    #pragma unroll
    for (int i = 0; i < 32; ++i) {
        unsigned e = ((unsigned)x16[2 * i] >> 7) & 0xFFu;
        sane += (e >= 100u && e <= 141u) ? 1 : 0;   // |v| in [2^-27, 2^14]
    }
    return sane < 24;
}

__device__ __forceinline__ bf16x8 ldb(const unsigned short* p) {
    return __builtin_bit_cast(bf16x8, *(const u16x8*)p);
}

// ---- pre-kernel: weights/biases -> bf16 in workspace (runs once, ~186 KB) ----
__global__ __launch_bounds__(256)
void conv_weights(const void* __restrict__ x,
                  const void* __restrict__ w_qkv, const void* __restrict__ b_qkv,
                  const void* __restrict__ w_proj, const void* __restrict__ b_proj,
                  unsigned short* __restrict__ ws)
{
    const bool f32m = sniff_fp32((const unsigned short*)x);
    int t = blockIdx.x * 256 + threadIdx.x;
    if (t >= WSTOT / 8) return;
    int off = t * 8;
    const void* src;
    int rel;
    if (off < WSBQ)      { src = w_qkv;  rel = off; }
    else if (off < WSP)  { src = b_qkv;  rel = off - WSBQ; }
    else if (off < WSBP) { src = w_proj; rel = off - WSP; }
    else                 { src = b_proj; rel = off - WSBP; }
    u16x8 v;
    if (f32m) {
        const float* p = (const float*)src + rel;
        f32x4 a = *(const f32x4*)p;
        f32x4 bb = *(const f32x4*)(p + 4);
        v[0] = f2bf(a[0]);  v[1] = f2bf(a[1]);  v[2] = f2bf(a[2]);  v[3] = f2bf(a[3]);
        v[4] = f2bf(bb[0]); v[5] = f2bf(bb[1]); v[6] = f2bf(bb[2]); v[7] = f2bf(bb[3]);
    } else {
        v = *(const u16x8*)((const unsigned short*)src + rel);
    }
    *(u16x8*)(ws + off) = v;
}

// ---- main fused kernel: one block per (b, window) ----
__global__ __launch_bounds__(256, 2)
void mua_main(const void* __restrict__ x,
              const unsigned short* __restrict__ ws,
              void* __restrict__ out)
{
    const int bid = blockIdx.x;
    const int b   = bid / NW;
    const int wi  = bid - b * NW;
    const int tid  = threadIdx.x;
    const int wave = tid >> 6;
    const int lane = tid & 63;
    const int quad = lane >> 4;
    const int l16  = lane & 15;

    // 31232 B LDS -> 5 blocks/CU. Region 1 (u16 [0,12288)) time-shared:
    //   x_s [64][104]              (dead after B2)
    //   k_s [2][64][96] swizzled   (written after B2, dead after B4)
    //   v_s [2][96][64] swizzled   (written after B4)
    // qp_s [2][16][104] @12288 (o_s [16][200]=3200 aliases; qp dead after qa reads)
    __shared__ __attribute__((aligned(16))) unsigned short lds[15616];
    unsigned short* x_s  = lds;
    unsigned short* k_s  = lds;
    unsigned short* v_s  = lds;
    unsigned short* qp_s = lds + 12288;
    unsigned short* o_s  = lds + 12288;

    // ---- preload wq tiles 0..2 (3-deep rotation, 36 regs) + all biases ----
    // Tile tt = nt*4 + wave: nt 0..2 -> q tiles (0..11), nt 3..5 -> k (12..23);
    // interleave balances q-pool vs k-store epilogue cost across waves.
    bf16x8 wq[3][3];
    float  biasq[6];
    #pragma unroll
    for (int nt = 0; nt < 3; ++nt) {
        const int c = (nt * 4 + wave) * 16 + l16;
        #pragma unroll
        for (int ks = 0; ks < 3; ++ks)
            wq[nt][ks] = ldb(ws + WSQ + c * 96 + ks * 32 + quad * 8);
    }
    #pragma unroll
    for (int nt = 0; nt < 6; ++nt)
        biasq[nt] = bf2f(ws[WSBQ + (nt * 4 + wave) * 16 + l16]);

    const bool f32m = sniff_fp32((const unsigned short*)x);

    // ---- phase 1: stage x tile (64 rows x 96, rows strided by 49*96 in global) ----
    {
        const size_t xoff = ((size_t)b * NTOK + wi) * DIM;
        if (f32m) {
            #pragma unroll
            for (int i = 0; i < 3; ++i) {
                int chunk = tid + i * 256;          // 768 = 64 rows * 12 chunks
                int row = chunk / 12;
                int c16 = chunk - row * 12;
                const float* p = (const float*)x + xoff + (size_t)row * (NW * DIM) + c16 * 8;
                f32x4 a = *(const f32x4*)p;
                f32x4 bb = *(const f32x4*)(p + 4);
                u16x8 r;
                r[0] = f2bf(a[0]);  r[1] = f2bf(a[1]);  r[2] = f2bf(a[2]);  r[3] = f2bf(a[3]);
                r[4] = f2bf(bb[0]); r[5] = f2bf(bb[1]); r[6] = f2bf(bb[2]); r[7] = f2bf(bb[3]);
                *(u16x8*)&x_s[row * 104 + c16 * 8] = r;
            }
        } else {
            #pragma unroll
            for (int i = 0; i < 3; ++i) {
                int chunk = tid + i * 256;
                int row = chunk / 12;
                int c16 = chunk - row * 12;
                const unsigned short* p = (const unsigned short*)x + xoff + (size_t)row * (NW * DIM) + c16 * 8;
                *(u16x8*)&x_s[row * 104 + c16 * 8] = *(const u16x8*)p;
            }
        }
    }
    __syncthreads();   // B1: x staged (also drains preloaded wq tiles)

    // ---- phase 2: A-fragments of x into registers (live until v-GEMM) ----
    bf16x8 afr[4][3];
    #pragma unroll
    for (int mt = 0; mt < 4; ++mt)
        #pragma unroll
        for (int ks = 0; ks < 3; ++ks)
            afr[mt][ks] = ldb(&x_s[(mt * 16 + l16) * 104 + ks * 32 + quad * 8]);
    __syncthreads();   // B2: x region free -> k may overwrite

    // ---- phase 3a: q+k channels; wq slot nt%3 refilled with tile nt+3 ----
    #pragma unroll
    for (int nt = 0; nt < 6; ++nt) {
        const int slot = nt % 3;   // compile-time after unroll
        f32x4 acc[4];
        #pragma unroll
        for (int mt = 0; mt < 4; ++mt) {
            acc[mt] = (f32x4){0.f, 0.f, 0.f, 0.f};
            #pragma unroll
            for (int ks = 0; ks < 3; ++ks)
                acc[mt] = __builtin_amdgcn_mfma_f32_16x16x32_bf16(afr[mt][ks], wq[slot][ks], acc[mt], 0, 0, 0);
        }
        if (nt < 3) {   // refill slot with tile nt+3 (WAR on slot orders after MFMAs)
            const int c2 = ((nt + 3) * 4 + wave) * 16 + l16;
            #pragma unroll
            for (int ks = 0; ks < 3; ++ks)
                wq[slot][ks] = ldb(ws + WSQ + c2 * 96 + ks * 32 + quad * 8);
        }
        // C-layout: col(channel) = l16, row(token) = quad*4 + r (+ mt*16)
        const int tt = nt * 4 + wave;
        const float bias = biasq[nt];
        if (nt < 3) {
            // q tiles: maxpool over the 4 M-tiles (pool groups are exactly mt)
            const int hd = tt / 6;
            const int d  = (tt % 6) * 16 + l16;
            #pragma unroll
            for (int r = 0; r < 4; ++r) {
                float m = fmaxf(fmaxf(acc[0][r], acc[1][r]), fmaxf(acc[2][r], acc[3][r])) + bias;
                qp_s[(hd * 16 + quad * 4 + r) * 104 + d] = f2bf(m);
            }
        } else {
            // K swizzled: col = ((d>>3)^(row&3))*8 + (d&7); row&3 == r here.
            const int tk = tt - 12;
            const int hd = tk / 6;
            const int dbh  = ((tk % 6) * 16) / 8 + (l16 >> 3);   // d>>3
            const int dlow = l16 & 7;
            #pragma unroll
            for (int mt = 0; mt < 4; ++mt)
                #pragma unroll
                for (int r = 0; r < 4; ++r)
                    k_s[hd * 6144 + (mt * 16 + quad * 4 + r) * 96 + ((dbh ^ r) << 3) + dlow]
                        = f2bf(acc[mt][r] + bias);
        }
    }
    __syncthreads();   // B3: qp/k ready

    // ---- phase 4: S^T = K @ qp^T (operand swap), per-lane softmax, P -> regs ----
    const int h   = wave >> 1;
    const int sub = wave & 1;
    bf16x8 qa[3];
    #pragma unroll
    for (int ks = 0; ks < 3; ++ks)
        qa[ks] = ldb(&qp_s[(h * 16 + l16) * 104 + ks * 32 + quad * 8]);
    // st[mt] C-layout: row = key (mt*16 + quad*4 + r), col = qrow (l16)
    f32x4 st[4];
    #pragma unroll
    for (int mt = 0; mt < 4; ++mt) st[mt] = (f32x4){0.f, 0.f, 0.f, 0.f};
    #pragma unroll
    for (int ks = 0; ks < 3; ++ks)
        #pragma unroll
        for (int mt = 0; mt < 4; ++mt) {
            bf16x8 kb = ldb(&k_s[h * 6144 + (mt * 16 + l16) * 96 + (((ks * 4 + quad) ^ (l16 & 3)) << 3)]);
            st[mt] = __builtin_amdgcn_mfma_f32_16x16x32_bf16(kb, qa[ks], st[mt], 0, 0, 0);
        }
    // softmax over the 16 per-lane values (all for qrow = l16) + cross-quad reduce
    const float cexp = 0.10206207261596576f * 1.4426950408889634f;  // 96^-0.5 * log2e
    float mx;
    {
        float m0 = fmaxf(fmaxf(st[0][0], st[0][1]), fmaxf(st[0][2], st[0][3]));
        float m1 = fmaxf(fmaxf(st[1][0], st[1][1]), fmaxf(st[1][2], st[1][3]));
        float m2 = fmaxf(fmaxf(st[2][0], st[2][1]), fmaxf(st[2][2], st[2][3]));
        float m3 = fmaxf(fmaxf(st[3][0], st[3][1]), fmaxf(st[3][2], st[3][3]));
        mx = fmaxf(fmaxf(m0, m1), fmaxf(m2, m3));
    }
    mx = fmaxf(mx, __shfl_xor(mx, 16));
    mx = fmaxf(mx, __shfl_xor(mx, 32));
    float e[4][4];
    #pragma unroll
    for (int mt = 0; mt < 4; ++mt)
        #pragma unroll
        for (int r = 0; r < 4; ++r)
            e[mt][r] = exp2f((st[mt][r] - mx) * cexp);
    float sum;
    {
        float s0 = (e[0][0] + e[0][1]) + (e[0][2] + e[0][3]);
        float s1 = (e[1][0] + e[1][1]) + (e[1][2] + e[1][3]);
        float s2 = (e[2][0] + e[2][1]) + (e[2][2] + e[2][3]);
        float s3 = (e[3][0] + e[3][1]) + (e[3][2] + e[3][3]);
        sum = (s0 + s1) + (s2 + s3);
    }
    sum += __shfl_xor(sum, 16);
    sum += __shfl_xor(sum, 32);
    const float rinv_l = 1.0f / sum;
    // redistribute rinv to O-epilogue layout (qrow = quad*4 + r)
    float rs[4];
    #pragma unroll
    for (int r = 0; r < 4; ++r)
        rs[r] = __shfl(rinv_l, (lane & 48) + quad * 4 + r);
    // assemble PV A-fragments in-register: pa[ks2] = P[qrow=l16][ks2*32+quad*8 ..+8]
    unsigned wlo[4], whi[4];
    #pragma unroll
    for (int mt = 0; mt < 4; ++mt) {
        wlo[mt] = (unsigned)f2bf(e[mt][0]) | ((unsigned)f2bf(e[mt][1]) << 16);
        whi[mt] = (unsigned)f2bf(e[mt][2]) | ((unsigned)f2bf(e[mt][3]) << 16);
    }
    bf16x8 pa[2];
    {
        const int srcA = ((quad & 1) * 2) * 16 + l16;   // first source quad-lane
        const int srcB = srcA + 16;                     // second source quad-lane
        const bool hiT = quad >= 2;                     // receiver tile = 2*ks2 + (quad>>1)
        #pragma unroll
        for (int ks2 = 0; ks2 < 2; ++ks2) {
            unsigned lo0a = __shfl(wlo[2 * ks2], srcA), lo0b = __shfl(wlo[2 * ks2 + 1], srcA);
            unsigned hi0a = __shfl(whi[2 * ks2], srcA), hi0b = __shfl(whi[2 * ks2 + 1], srcA);
            unsigned lo1a = __shfl(wlo[2 * ks2], srcB), lo1b = __shfl(wlo[2 * ks2 + 1], srcB);
            unsigned hi1a = __shfl(whi[2 * ks2], srcB), hi1b = __shfl(whi[2 * ks2 + 1], srcB);
            u32x4 W;
            W[0] = hiT ? lo0b : lo0a;
            W[1] = hiT ? hi0b : hi0a;
            W[2] = hiT ? lo1b : lo1a;
            W[3] = hiT ? hi1b : hi1a;
            pa[ks2] = __builtin_bit_cast(bf16x8, W);
        }
    }

    // ---- preload v-weight tiles 0,1 (2-deep rotation); hide under B4 wait ----
    bf16x8 wv[2][3];
    float  biasv[3];
    #pragma unroll
    for (int i = 0; i < 2; ++i) {
        const int c = 384 + (i * 4 + wave) * 16 + l16;
        #pragma unroll
        for (int ks = 0; ks < 3; ++ks)
            wv[i][ks] = ldb(ws + WSQ + c * 96 + ks * 32 + quad * 8);
    }
    #pragma unroll
    for (int i = 0; i < 3; ++i)
        biasv[i] = bf2f(ws[WSBQ + 384 + (i * 4 + wave) * 16 + l16]);
    __syncthreads();   // B4: all k reads done -> v may overwrite region 1

    // ---- phase 3b: v channels (afr still in regs); v swizzled [head][d][t] ----
    #pragma unroll
    for (int i = 0; i < 3; ++i) {
        const int slot = i & 1;   // compile-time after unroll
        f32x4 acc[4];
        #pragma unroll
        for (int mt = 0; mt < 4; ++mt) {
            acc[mt] = (f32x4){0.f, 0.f, 0.f, 0.f};
            #pragma unroll
            for (int ks = 0; ks < 3; ++ks)
                acc[mt] = __builtin_amdgcn_mfma_f32_16x16x32_bf16(afr[mt][ks], wv[slot][ks], acc[mt], 0, 0, 0);
        }
        if (i == 0) {   // refill slot 0 with tile 2
            const int c2 = 384 + (2 * 4 + wave) * 16 + l16;
            #pragma unroll
            for (int ks = 0; ks < 3; ++ks)
                wv[0][ks] = ldb(ws + WSQ + c2 * 96 + ks * 32 + quad * 8);
        }
        const int tv = i * 4 + wave;
        const int hd = tv / 6;
        const int d  = (tv % 6) * 16 + l16;
        const float bias = biasv[i];
        #pragma unroll
        for (int mt = 0; mt < 4; ++mt) {
            u16x4 pk;
            #pragma unroll
            for (int r = 0; r < 4; ++r) pk[r] = f2bf(acc[mt][r] + bias);
            const int tb = 2 * mt + (quad >> 1);     // t-block of t = mt*16 + quad*4
            *(u16x4*)&v_s[hd * 6144 + d * 64 + ((tb ^ (d & 7)) << 3) + (quad & 1) * 4] = pk;
        }
    }

    // ---- hoist proj weights/biases (afr/wv dead); land under B4b + PV ----
    const int cbase = wave * 48;
    bf16x8 wpr[3][6];
    float  biasp[3];
    #pragma unroll
    for (int i = 0; i < 3; ++i) {
        const int c = cbase + i * 16 + l16;
        #pragma unroll
        for (int ks = 0; ks < 6; ++ks)
            wpr[i][ks] = ldb(ws + WSP + c * 192 + ks * 32 + quad * 8);
        biasp[i] = bf2f(ws[WSBP + c]);
    }
    __syncthreads();   // B4b: v ready

    // ---- phase 5: O = P @ V (3 of 6 d-tiles per sub-wave), scale rows by rinv ----
    #pragma unroll
    for (int i = 0; i < 3; ++i) {
        const int n0 = (sub * 3 + i) * 16;
        f32x4 oacc = (f32x4){0.f, 0.f, 0.f, 0.f};
        #pragma unroll
        for (int ks2 = 0; ks2 < 2; ++ks2) {
            bf16x8 vb = ldb(&v_s[h * 6144 + (n0 + l16) * 64 + (((ks2 * 4 + quad) ^ (l16 & 7)) << 3)]);
            oacc = __builtin_amdgcn_mfma_f32_16x16x32_bf16(pa[ks2], vb, oacc, 0, 0, 0);
        }
        #pragma unroll
        for (int r = 0; r < 4; ++r)
            o_s[(quad * 4 + r) * 200 + h * 96 + n0 + l16] = f2bf(oacc[r] * rs[r]);
    }
    __syncthreads();   // B5: o ready

    // ---- phase 6: out = o @ w_proj^T + b_proj; wave owns 48 of 192 channels ----
    bf16x8 oa[6];
    #pragma unroll
    for (int ks = 0; ks < 6; ++ks)
        oa[ks] = ldb(&o_s[l16 * 200 + ks * 32 + quad * 8]);
    #pragma unroll
    for (int i = 0; i < 3; ++i) {
        const int c = cbase + i * 16 + l16;
        f32x4 acc = (f32x4){0.f, 0.f, 0.f, 0.f};
        #pragma unroll
        for (int ks = 0; ks < 6; ++ks)
            acc = __builtin_amdgcn_mfma_f32_16x16x32_bf16(oa[ks], wpr[i][ks], acc, 0, 0, 0);
        const float bias = biasp[i];
        #pragma unroll
        for (int r = 0; r < 4; ++r) {
            const int m = quad * 4 + r;          // out row = b*784 + m*49 + wi
            const size_t idx = ((size_t)(b * 784 + m * NW + wi)) * DOUT + c;
            if (f32m) ((float*)out)[idx] = acc[r] + bias;
            else      ((unsigned short*)out)[idx] = f2bf(acc[r] + bias);
        }
    }
}

extern "C" void kernel_launch(void* const* d_in, const int* in_sizes, int n_in,
                              void* d_out, int out_size, void* d_ws, size_t ws_size,
                              hipStream_t stream) {
    const void* x      = d_in[0];
    const void* w_qkv  = d_in[1];
    const void* b_qkv  = d_in[2];
    const void* w_proj = d_in[3];
    const void* b_proj = d_in[4];
    unsigned short* ws = (unsigned short*)d_ws;

    // Pre-kernel: convert weights/biases to bf16 into workspace (stream-ordered).
    dim3 gridc((WSTOT / 8 + 255) / 256), blockc(256);
    hipLaunchKernelGGL(conv_weights, gridc, blockc, 0, stream,
                       x, w_qkv, b_qkv, w_proj, b_proj, ws);

    dim3 grid(64 * NW), block(256);
    hipLaunchKernelGGL(mua_main, grid, block, 0, stream, x, ws, d_out);
}